// Round 9
// baseline (11655.688 us; speedup 1.0000x reference)
//
#include <hip/hip_runtime.h>

#define T_SEQ  1024
#define NBATCH 512
#define IN_DIM 16
#define HDIM   128
#define G4     (4 * HDIM)
#define NWG_ROLE 128   // WGs per role; 4 batches per WG

typedef unsigned short ushort_t;
typedef __attribute__((ext_vector_type(8))) _Float16 f16x8;
typedef __attribute__((ext_vector_type(4))) float f32x4;

#define MFMA16(a, b, c) __builtin_amdgcn_mfma_f32_16x16x32_f16((a), (b), (c), 0, 0, 0)

__device__ __forceinline__ float sigf(float x) {
  return __builtin_amdgcn_rcpf(1.0f + __expf(-x));
}
__device__ __forceinline__ float tanhf_fast(float x) {
  return 1.0f - 2.0f * __builtin_amdgcn_rcpf(1.0f + __expf(2.0f * x));
}
__device__ __forceinline__ ushort_t f16_bits(float f) {
  const _Float16 h = (_Float16)f;
  return __builtin_bit_cast(unsigned short, h);
}
__device__ __forceinline__ void split_f16(float f, ushort_t* hi, ushort_t* lo) {
  const _Float16 h = (_Float16)f;
  *hi = __builtin_bit_cast(unsigned short, h);
  const _Float16 l = (_Float16)(f - (float)h);
  *lo = __builtin_bit_cast(unsigned short, l);
}
// barrier that waits only on LDS ops (global stores stay in flight)
__device__ __forceinline__ void bar_lds() {
  asm volatile("s_waitcnt lgkmcnt(0)\n\ts_barrier" ::: "memory");
}
__device__ __forceinline__ void spin_on(const int* p) {
  while (__hip_atomic_load(p, __ATOMIC_ACQUIRE, __HIP_MEMORY_SCOPE_AGENT) == 0)
    __builtin_amdgcn_s_sleep(8);
}

// ---------------- prep: split weights into fp16 hi/lo ----------------
__global__ __launch_bounds__(256) void prep_weights(
    const float* __restrict__ Whh0, const float* __restrict__ Whh1,
    const float* __restrict__ Wih0, const float* __restrict__ Wih1,
    ushort_t* __restrict__ w0h, ushort_t* __restrict__ w0l,
    ushort_t* __restrict__ w1h, ushort_t* __restrict__ w1l,
    ushort_t* __restrict__ wxh, ushort_t* __restrict__ wxl,
    ushort_t* __restrict__ wi1h, ushort_t* __restrict__ wi1l)
{
  const int idx = blockIdx.x * 256 + threadIdx.x;
  if (idx < 512 * HDIM) {
    split_f16(Whh0[idx], &w0h[idx], &w0l[idx]);
    split_f16(Whh1[idx], &w1h[idx], &w1l[idx]);
    split_f16(Wih1[idx], &wi1h[idx], &wi1l[idx]);
  }
  if (idx < 512 * 32) {  // Wih0 zero-padded K=16 -> 32
    const int g = idx >> 5, k = idx & 31;
    const float f = (k < IN_DIM) ? Wih0[g * IN_DIM + k] : 0.0f;
    split_f16(f, &wxh[idx], &wxl[idx]);
  }
}

// ---------------- fused persistent pipeline kernel ----------------
// 256 WGs x 512 threads, all resident (1 WG/CU). WGs [0,128) = layer-0 role,
// WGs [128,256) = layer-1 role (gx1 GEMM + recurrence + FC). L1-WG w consumes
// exactly L0-WG w's 4 batches -> pairwise flags; h1buf double-buffered with
// lag-2 backpressure. Gate cols permuted (g = i*128 + wv*16 + row) so a kq==0
// lane holds all 4 gates for hidden j = wv*16+row, 4 batches (C rows 0-3).
__global__ __launch_bounds__(512, 2) void lstm_fused(
    const float* __restrict__ x,
    const ushort_t* __restrict__ w0h, const ushort_t* __restrict__ w0l,
    const ushort_t* __restrict__ wxh, const ushort_t* __restrict__ wxl,
    const float* __restrict__ bih0, const float* __restrict__ bhh0,
    const ushort_t* __restrict__ wi1h, const ushort_t* __restrict__ wi1l,
    const ushort_t* __restrict__ w1h, const ushort_t* __restrict__ w1l,
    const float* __restrict__ bih1, const float* __restrict__ bhh1,
    const float* __restrict__ Wfc, const float* __restrict__ bfc,
    float* __restrict__ out,
    ushort_t* __restrict__ h1buf,   // [2][Tc*NBATCH*HDIM] fp16
    float* __restrict__ gx1buf,     // [Tc*NBATCH][128][4]  (m, j, gate)
    int* __restrict__ flags, int Tc, int tcshift, int nchunk)
{
  const int wgid = blockIdx.x;
  const int tid  = threadIdx.x;
  const int lane = tid & 63;
  const int wv   = tid >> 6;
  const int row  = lane & 15;
  const int kq   = lane >> 4;
  const bool upd = (kq == 0);
  const int j    = wv * 16 + row;
  const size_t chunkElems = (size_t)Tc * NBATCH * HDIM;

  __shared__ __align__(16) ushort_t hfrag[2][4][144];
  __shared__ __align__(16) ushort_t xlds[4][128][32];
  __shared__ float pl[2][8][4];

  int* l0done = flags;                       // [nchunk][128]
  int* gxdone = flags + nchunk * NWG_ROLE;   // [nchunk][128]

  if (wgid < NWG_ROLE) {
    // ================= L0 ROLE =================
    const int w  = wgid;
    const int b0 = w * 4;
    f16x8 Bh[4][4], Bl[4][4], Bxh[4], Bxl[4];
#pragma unroll
    for (int i = 0; i < 4; ++i) {
      const int g = i * 128 + j;
#pragma unroll
      for (int kt = 0; kt < 4; ++kt) {
        const int off = g * HDIM + kt * 32 + kq * 8;
        Bh[i][kt] = *(const f16x8*)&w0h[off];
        Bl[i][kt] = *(const f16x8*)&w0l[off];
      }
      Bxh[i] = *(const f16x8*)&wxh[g * 32 + kq * 8];
      Bxl[i] = *(const f16x8*)&wxl[g * 32 + kq * 8];
    }
    float bz[4];
#pragma unroll
    for (int i = 0; i < 4; ++i) bz[i] = bih0[i * 128 + j] + bhh0[i * 128 + j];

    float hc[4] = {0.f, 0.f, 0.f, 0.f}, cc[4] = {0.f, 0.f, 0.f, 0.f};
    for (int q = tid; q < 2 * 4 * 144; q += 512) ((ushort_t*)hfrag)[q] = 0;
    __syncthreads();

    int cur = 0;
    for (int ch = 0; ch < nchunk; ++ch) {
      if (ch >= 2) spin_on(&gxdone[(ch - 2) * NWG_ROLE + w]);
      const int t0 = ch << tcshift;
      // stage this chunk's x as fp16 (pad K 16->32 with zeros)
      for (int q = tid; q < 4 * Tc; q += 512) {
        const int b  = q >> tcshift;
        const int ts = q & (Tc - 1);
        const float* src = &x[((size_t)(b0 + b) * T_SEQ + t0 + ts) * IN_DIM];
        const float4 v0 = *(const float4*)&src[0];
        const float4 v1 = *(const float4*)&src[4];
        const float4 v2 = *(const float4*)&src[8];
        const float4 v3 = *(const float4*)&src[12];
        ushort_t* dst = &xlds[b][ts][0];
        dst[0]  = f16_bits(v0.x); dst[1]  = f16_bits(v0.y);
        dst[2]  = f16_bits(v0.z); dst[3]  = f16_bits(v0.w);
        dst[4]  = f16_bits(v1.x); dst[5]  = f16_bits(v1.y);
        dst[6]  = f16_bits(v1.z); dst[7]  = f16_bits(v1.w);
        dst[8]  = f16_bits(v2.x); dst[9]  = f16_bits(v2.y);
        dst[10] = f16_bits(v2.z); dst[11] = f16_bits(v2.w);
        dst[12] = f16_bits(v3.x); dst[13] = f16_bits(v3.y);
        dst[14] = f16_bits(v3.z); dst[15] = f16_bits(v3.w);
        *(float4*)&dst[16] = (float4){0.f, 0.f, 0.f, 0.f};
        *(float4*)&dst[24] = (float4){0.f, 0.f, 0.f, 0.f};
      }
      __syncthreads();

      ushort_t* hb = h1buf + (size_t)(ch & 1) * chunkElems;
      for (int tt = 0; tt < Tc; ++tt) {
        const f16x8 ax = *(const f16x8*)&xlds[lane & 3][tt][kq * 8];
        f32x4 acc[4];
#pragma unroll
        for (int i = 0; i < 4; ++i) acc[i] = (f32x4){0.f, 0.f, 0.f, 0.f};
#pragma unroll
        for (int kt = 0; kt < 4; ++kt) {
          const f16x8 ah = *(const f16x8*)&hfrag[cur][lane & 3][kt * 32 + kq * 8];
#pragma unroll
          for (int i = 0; i < 4; ++i) acc[i] = MFMA16(ah, Bh[i][kt], acc[i]);
#pragma unroll
          for (int i = 0; i < 4; ++i) acc[i] = MFMA16(ah, Bl[i][kt], acc[i]);
        }
#pragma unroll
        for (int i = 0; i < 4; ++i) acc[i] = MFMA16(ax, Bxh[i], acc[i]);
#pragma unroll
        for (int i = 0; i < 4; ++i) acc[i] = MFMA16(ax, Bxl[i], acc[i]);

        if (upd) {
#pragma unroll
          for (int b = 0; b < 4; ++b) {
            const float ig = sigf(acc[0][b] + bz[0]);
            const float fg = sigf(acc[1][b] + bz[1]);
            const float gg = tanhf_fast(acc[2][b] + bz[2]);
            const float og = sigf(acc[3][b] + bz[3]);
            cc[b] = fg * cc[b] + ig * gg;
            hc[b] = og * tanhf_fast(cc[b]);
            const ushort_t hbits = f16_bits(hc[b]);
            hfrag[cur ^ 1][b][j] = hbits;
            hb[((size_t)tt * NBATCH + b0 + b) * HDIM + j] = hbits;
          }
        }
        bar_lds();
        cur ^= 1;
      }
      __syncthreads();  // drains vmcnt per wave -> h1buf chunk complete
      if (tid == 0)
        __hip_atomic_store(&l0done[ch * NWG_ROLE + w], 1, __ATOMIC_RELEASE,
                           __HIP_MEMORY_SCOPE_AGENT);
    }
  } else {
    // ================= L1 ROLE =================
    const int w  = wgid - NWG_ROLE;
    const int b0 = w * 4;
    float bz1[4];
#pragma unroll
    for (int i = 0; i < 4; ++i) bz1[i] = bih1[i * 128 + j] + bhh1[i * 128 + j];
    const float wfc  = Wfc[j];
    const float bfcv = bfc[0];
    float hc[4] = {0.f, 0.f, 0.f, 0.f}, cc[4] = {0.f, 0.f, 0.f, 0.f};
    for (int q = tid; q < 2 * 4 * 144; q += 512) ((ushort_t*)hfrag)[q] = 0;
    __syncthreads();

    int cur = 0;
    for (int ch = 0; ch < nchunk; ++ch) {
      spin_on(&l0done[ch * NWG_ROLE + w]);
      const ushort_t* hb = h1buf + (size_t)(ch & 1) * chunkElems;

      // ---- GEMM phase: gx1 rows for own 4 batches (WG-private) ----
      {
        f16x8 Gh[4][4], Gl[4][4];
#pragma unroll
        for (int i = 0; i < 4; ++i) {
          const int g = i * 128 + j;
#pragma unroll
          for (int kt = 0; kt < 4; ++kt) {
            const int off = g * HDIM + kt * 32 + kq * 8;
            Gh[i][kt] = *(const f16x8*)&wi1h[off];
            Gl[i][kt] = *(const f16x8*)&wi1l[off];
          }
        }
        const int nMt = Tc >> 2;  // 16-row M-tiles = 4 tt x 4 batches
        for (int mt = 0; mt < nMt; ++mt) {
          const int att = mt * 4 + (row >> 2);
          const size_t aoff =
              ((size_t)att * NBATCH + b0 + (row & 3)) * HDIM + kq * 8;
          f32x4 acc[4];
#pragma unroll
          for (int i = 0; i < 4; ++i) acc[i] = (f32x4){0.f, 0.f, 0.f, 0.f};
#pragma unroll
          for (int kt = 0; kt < 4; ++kt) {
            const f16x8 a = *(const f16x8*)&hb[aoff + kt * 32];
#pragma unroll
            for (int i = 0; i < 4; ++i) acc[i] = MFMA16(a, Gh[i][kt], acc[i]);
#pragma unroll
            for (int i = 0; i < 4; ++i) acc[i] = MFMA16(a, Gl[i][kt], acc[i]);
          }
#pragma unroll
          for (int r = 0; r < 4; ++r) {
            const int mr  = kq * 4 + r;      // C row
            const int stt = mt * 4 + (mr >> 2);
            const int sb  = mr & 3;
            float4 o;
            o.x = acc[0][r] + bz1[0];
            o.y = acc[1][r] + bz1[1];
            o.z = acc[2][r] + bz1[2];
            o.w = acc[3][r] + bz1[3];
            *(float4*)&gx1buf[(((size_t)stt * NBATCH + b0 + sb) * 128 + j) * 4] = o;
          }
        }
      }
      __syncthreads();  // gemm stores drained before recurrent reads

      // ---- recurrent phase + fused FC ----
      {
        f16x8 Rh[4][4], Rl[4][4];
#pragma unroll
        for (int i = 0; i < 4; ++i) {
          const int g = i * 128 + j;
#pragma unroll
          for (int kt = 0; kt < 4; ++kt) {
            const int off = g * HDIM + kt * 32 + kq * 8;
            Rh[i][kt] = *(const f16x8*)&w1h[off];
            Rl[i][kt] = *(const f16x8*)&w1l[off];
          }
        }
        const int t0 = ch << tcshift;
        for (int tt = 0; tt < Tc; ++tt) {
          float4 zc[4];
          if (upd) {
#pragma unroll
            for (int b = 0; b < 4; ++b)
              zc[b] = *(const float4*)
                  &gx1buf[(((size_t)tt * NBATCH + b0 + b) * 128 + j) * 4];
          }
          f32x4 acc[4];
#pragma unroll
          for (int i = 0; i < 4; ++i) acc[i] = (f32x4){0.f, 0.f, 0.f, 0.f};
#pragma unroll
          for (int kt = 0; kt < 4; ++kt) {
            const f16x8 ah =
                *(const f16x8*)&hfrag[cur][lane & 3][kt * 32 + kq * 8];
#pragma unroll
            for (int i = 0; i < 4; ++i) acc[i] = MFMA16(ah, Rh[i][kt], acc[i]);
#pragma unroll
            for (int i = 0; i < 4; ++i) acc[i] = MFMA16(ah, Rl[i][kt], acc[i]);
          }
          if (upd) {
            float p[4];
#pragma unroll
            for (int b = 0; b < 4; ++b) {
              const float ig = sigf(acc[0][b] + zc[b].x);
              const float fg = sigf(acc[1][b] + zc[b].y);
              const float gg = tanhf_fast(acc[2][b] + zc[b].z);
              const float og = sigf(acc[3][b] + zc[b].w);
              cc[b] = fg * cc[b] + ig * gg;
              hc[b] = og * tanhf_fast(cc[b]);
              hfrag[cur ^ 1][b][j] = f16_bits(hc[b]);
              p[b] = fmaxf(hc[b], 0.0f) * wfc;
            }
#pragma unroll
            for (int m = 1; m < 16; m <<= 1) {
#pragma unroll
              for (int b = 0; b < 4; ++b) p[b] += __shfl_xor(p[b], m, 64);
            }
            if (row == 0) {
#pragma unroll
              for (int b = 0; b < 4; ++b) pl[cur][wv][b] = p[b];
            }
          }
          bar_lds();
          if (tid < 4) {
            float s = bfcv;
#pragma unroll
            for (int w8 = 0; w8 < 8; ++w8) s += pl[cur][w8][tid];
            out[(size_t)(b0 + tid) * T_SEQ + t0 + tt] = fmaxf(s, 0.0f);
          }
          cur ^= 1;
        }
      }
      __syncthreads();  // h1 reads done; safe for producer to overwrite
      if (tid == 0)
        __hip_atomic_store(&gxdone[ch * NWG_ROLE + w], 1, __ATOMIC_RELEASE,
                           __HIP_MEMORY_SCOPE_AGENT);
    }
  }
}

extern "C" void kernel_launch(void* const* d_in, const int* in_sizes, int n_in,
                              void* d_out, int out_size, void* d_ws, size_t ws_size,
                              hipStream_t stream)
{
  const float* x    = (const float*)d_in[0];
  const float* Wih0 = (const float*)d_in[1];
  const float* Whh0 = (const float*)d_in[2];
  const float* bih0 = (const float*)d_in[3];
  const float* bhh0 = (const float*)d_in[4];
  const float* Wih1 = (const float*)d_in[5];
  const float* Whh1 = (const float*)d_in[6];
  const float* bih1 = (const float*)d_in[7];
  const float* bhh1 = (const float*)d_in[8];
  const float* Wfc  = (const float*)d_in[9];
  const float* bfc  = (const float*)d_in[10];
  float* out = (float*)d_out;

  char* base = (char*)d_ws;
  int* flags = (int*)base;  // 64 KiB reserved (2 x nchunk x 128 ints, nchunk<=64)
  ushort_t* w0h  = (ushort_t*)(base + 65536);
  ushort_t* w0l  = w0h  + 65536;
  ushort_t* w1h  = w0l  + 65536;
  ushort_t* w1l  = w1h  + 65536;
  ushort_t* wi1h = w1l  + 65536;
  ushort_t* wi1l = wi1h + 65536;
  ushort_t* wxh  = wi1l + 65536;
  ushort_t* wxl  = wxh  + 16384;
  ushort_t* h1buf = wxl + 16384;  // byte offset 917504

  int Tc = 128, tcshift = 7;
  while (Tc > 16) {
    const size_t need = 917504ull +
        (size_t)Tc * (2ull * NBATCH * HDIM * 2 + (size_t)NBATCH * G4 * 4);
    if (need <= ws_size) break;
    Tc >>= 1;
    --tcshift;
  }
  const int nchunk = T_SEQ / Tc;
  float* gx1buf = (float*)(h1buf + (size_t)2 * Tc * NBATCH * HDIM);

  (void)hipMemsetAsync(d_ws, 0, 65536, stream);  // clear sync flags
  hipLaunchKernelGGL(prep_weights, dim3(256), dim3(256), 0, stream,
                     Whh0, Whh1, Wih0, Wih1,
                     w0h, w0l, w1h, w1l, wxh, wxl, wi1h, wi1l);
  hipLaunchKernelGGL(lstm_fused, dim3(2 * NWG_ROLE), dim3(512), 0, stream,
                     x, w0h, w0l, wxh, wxl, bih0, bhh0,
                     wi1h, wi1l, w1h, w1l, bih1, bhh1, Wfc, bfc,
                     out, h1buf, gx1buf, flags, Tc, tcshift, nchunk);
}

// Round 10
// 2076.657 us; speedup vs baseline: 5.6127x; 5.6127x over previous
//
#include <hip/hip_runtime.h>

#define T_SEQ  1024
#define NBATCH 512
#define IN_DIM 16
#define HDIM   128
#define G4     (4 * HDIM)
#define TC     64
#define NCHUNK (T_SEQ / TC)
#define NWGH   128   // WGs per role; 4 batches per WG

typedef unsigned short ushort_t;
typedef __attribute__((ext_vector_type(8))) _Float16 f16x8;
typedef __attribute__((ext_vector_type(4))) float f32x4;

#define MFMA16(a, b, c) __builtin_amdgcn_mfma_f32_16x16x32_f16((a), (b), (c), 0, 0, 0)

__device__ __forceinline__ float sigf(float x) {
  return __builtin_amdgcn_rcpf(1.0f + __expf(-x));
}
__device__ __forceinline__ float tanhf_fast(float x) {
  return 1.0f - 2.0f * __builtin_amdgcn_rcpf(1.0f + __expf(2.0f * x));
}
__device__ __forceinline__ ushort_t f16_bits(float f) {
  const _Float16 h = (_Float16)f;
  return __builtin_bit_cast(unsigned short, h);
}
__device__ __forceinline__ void split_f16(float f, ushort_t* hi, ushort_t* lo) {
  const _Float16 h = (_Float16)f;
  *hi = __builtin_bit_cast(unsigned short, h);
  const _Float16 l = (_Float16)(f - (float)h);
  *lo = __builtin_bit_cast(unsigned short, l);
}
// barrier that waits only on LDS ops (global stores stay in flight)
__device__ __forceinline__ void bar_lds() {
  asm volatile("s_waitcnt lgkmcnt(0)\n\ts_barrier" ::: "memory");
}

// ---------------- prep: split weights into fp16 hi/lo ----------------
__global__ __launch_bounds__(256) void prep_weights(
    const float* __restrict__ Whh0, const float* __restrict__ Whh1,
    const float* __restrict__ Wih0, const float* __restrict__ Wih1,
    ushort_t* __restrict__ w0h, ushort_t* __restrict__ w0l,
    ushort_t* __restrict__ w1h, ushort_t* __restrict__ w1l,
    ushort_t* __restrict__ wxh, ushort_t* __restrict__ wxl,
    ushort_t* __restrict__ wi1h, ushort_t* __restrict__ wi1l)
{
  const int idx = blockIdx.x * 256 + threadIdx.x;
  if (idx < 512 * HDIM) {
    split_f16(Whh0[idx], &w0h[idx], &w0l[idx]);
    split_f16(Whh1[idx], &w1h[idx], &w1l[idx]);
    split_f16(Wih1[idx], &wi1h[idx], &wi1l[idx]);
  }
  if (idx < 512 * 32) {  // Wih0 zero-padded K=16 -> 32
    const int g = idx >> 5, k = idx & 31;
    const float f = (k < IN_DIM) ? Wih0[g * IN_DIM + k] : 0.0f;
    split_f16(f, &wxh[idx], &wxl[idx]);
  }
}

// ---------------- pipelined launch: l0(ch) on WGs [0,128), gemm+l1(ch-1) on
// WGs [128,256). Coherence of h1buf handoff comes from the kernel boundary
// between launches (no intra-kernel cross-WG sync at all). Gate columns
// permuted (g = i*128 + wv*16 + row) so a kq==0 lane holds all 4 gate types
// for hidden j = wv*16+row, 4 batches (C rows 0-3) -> in-lane LSTM update.
__global__ __launch_bounds__(512, 2) void lstm_pipe(
    const float* __restrict__ x,
    const ushort_t* __restrict__ w0h, const ushort_t* __restrict__ w0l,
    const ushort_t* __restrict__ wxh, const ushort_t* __restrict__ wxl,
    const float* __restrict__ bih0, const float* __restrict__ bhh0,
    const ushort_t* __restrict__ wi1h, const ushort_t* __restrict__ wi1l,
    const ushort_t* __restrict__ w1h, const ushort_t* __restrict__ w1l,
    const float* __restrict__ bih1, const float* __restrict__ bhh1,
    const float* __restrict__ Wfc, const float* __restrict__ bfc,
    float* __restrict__ out,
    float* __restrict__ h1s, float* __restrict__ c1s,
    float* __restrict__ h2s, float* __restrict__ c2s,
    ushort_t* __restrict__ h1buf,   // [2][NWGH][TC*4][HDIM] fp16
    float* __restrict__ gx1buf,     // [NWGH][TC*4][HDIM][4]
    int ch)
{
  const int tid  = threadIdx.x;
  const int lane = tid & 63;
  const int wv   = tid >> 6;
  const int row  = lane & 15;
  const int kq   = lane >> 4;
  const bool upd = (kq == 0);
  const int j    = wv * 16 + row;

  if (blockIdx.x < NWGH) {
    // ================= L0 ROLE: chunk ch =================
    if (ch >= NCHUNK) return;
    const int w  = blockIdx.x;
    const int b0 = w * 4;

    __shared__ __align__(16) ushort_t hfrag[2][4][136];
    __shared__ __align__(16) ushort_t xlds[4][TC][32];

    f16x8 Bh[4][4], Bl[4][4], Bxh[4], Bxl[4];
#pragma unroll
    for (int i = 0; i < 4; ++i) {
      const int g = i * 128 + j;
#pragma unroll
      for (int kt = 0; kt < 4; ++kt) {
        const int off = g * HDIM + kt * 32 + kq * 8;
        Bh[i][kt] = *(const f16x8*)&w0h[off];
        Bl[i][kt] = *(const f16x8*)&w0l[off];
      }
      Bxh[i] = *(const f16x8*)&wxh[g * 32 + kq * 8];
      Bxl[i] = *(const f16x8*)&wxl[g * 32 + kq * 8];
    }

    // stage this chunk's x as fp16 (2 threads per (b,ts) row)
    {
      const int r = tid >> 1, half = tid & 1;
      const int b = r >> 6, ts = r & (TC - 1);
      const float* src =
          &x[((size_t)(b0 + b) * T_SEQ + ch * TC + ts) * IN_DIM + half * 8];
      const float4 v0 = *(const float4*)&src[0];
      const float4 v1 = *(const float4*)&src[4];
      ushort_t* dst = &xlds[b][ts][half * 8];
      dst[0] = f16_bits(v0.x); dst[1] = f16_bits(v0.y);
      dst[2] = f16_bits(v0.z); dst[3] = f16_bits(v0.w);
      dst[4] = f16_bits(v1.x); dst[5] = f16_bits(v1.y);
      dst[6] = f16_bits(v1.z); dst[7] = f16_bits(v1.w);
      *(float4*)&xlds[b][ts][16 + half * 8] = (float4){0.f, 0.f, 0.f, 0.f};
    }

    float bz[4] = {0, 0, 0, 0};
    float hc[4] = {0, 0, 0, 0}, cc[4] = {0, 0, 0, 0};
    if (upd) {
#pragma unroll
      for (int i = 0; i < 4; ++i) bz[i] = bih0[i * 128 + j] + bhh0[i * 128 + j];
#pragma unroll
      for (int b = 0; b < 4; ++b) {
        hc[b] = h1s[(size_t)(b0 + b) * HDIM + j];
        cc[b] = c1s[(size_t)(b0 + b) * HDIM + j];
        hfrag[0][b][j] = f16_bits(hc[b]);
      }
    }
    __syncthreads();

    ushort_t* hb = h1buf + ((size_t)(ch & 1) * NWGH + w) * (TC * 4 * HDIM);
    int cur = 0;
    for (int tt = 0; tt < TC; ++tt) {
      const f16x8 ax = *(const f16x8*)&xlds[lane & 3][tt][kq * 8];
      f32x4 acc[4];
#pragma unroll
      for (int i = 0; i < 4; ++i) acc[i] = (f32x4){0.f, 0.f, 0.f, 0.f};
#pragma unroll
      for (int kt = 0; kt < 4; ++kt) {
        const f16x8 ah = *(const f16x8*)&hfrag[cur][lane & 3][kt * 32 + kq * 8];
#pragma unroll
        for (int i = 0; i < 4; ++i) acc[i] = MFMA16(ah, Bh[i][kt], acc[i]);
#pragma unroll
        for (int i = 0; i < 4; ++i) acc[i] = MFMA16(ah, Bl[i][kt], acc[i]);
      }
#pragma unroll
      for (int i = 0; i < 4; ++i) acc[i] = MFMA16(ax, Bxh[i], acc[i]);
#pragma unroll
      for (int i = 0; i < 4; ++i) acc[i] = MFMA16(ax, Bxl[i], acc[i]);

      if (upd) {
#pragma unroll
        for (int b = 0; b < 4; ++b) {
          const float ig = sigf(acc[0][b] + bz[0]);
          const float fg = sigf(acc[1][b] + bz[1]);
          const float gg = tanhf_fast(acc[2][b] + bz[2]);
          const float og = sigf(acc[3][b] + bz[3]);
          cc[b] = fg * cc[b] + ig * gg;
          hc[b] = og * tanhf_fast(cc[b]);
          const ushort_t hbits = f16_bits(hc[b]);
          hfrag[cur ^ 1][b][j] = hbits;
          hb[(size_t)(tt * 4 + b) * HDIM + j] = hbits;
        }
      }
      bar_lds();
      cur ^= 1;
    }
    if (upd) {
#pragma unroll
      for (int b = 0; b < 4; ++b) {
        h1s[(size_t)(b0 + b) * HDIM + j] = hc[b];
        c1s[(size_t)(b0 + b) * HDIM + j] = cc[b];
      }
    }
  } else {
    // ================= L1 ROLE: gemm + recurrence + FC, chunk ch-1 =========
    if (ch == 0) return;
    const int w  = blockIdx.x - NWGH;
    const int b0 = w * 4;

    __shared__ __align__(16) ushort_t hfrag1[2][4][136];
    __shared__ float pl[2][8][4];

    const ushort_t* hb =
        h1buf + ((size_t)((ch - 1) & 1) * NWGH + w) * (TC * 4 * HDIM);
    float* gx = gx1buf + (size_t)w * (TC * 4 * HDIM * 4);

    // ---- gemm: gx1 = h1 . Wih1^T + biases, own 4 batches only ----
    {
      f16x8 Gh[4][4], Gl[4][4];
      float bz1[4];
#pragma unroll
      for (int i = 0; i < 4; ++i) {
        const int g = i * 128 + j;
#pragma unroll
        for (int kt = 0; kt < 4; ++kt) {
          const int off = g * HDIM + kt * 32 + kq * 8;
          Gh[i][kt] = *(const f16x8*)&wi1h[off];
          Gl[i][kt] = *(const f16x8*)&wi1l[off];
        }
        bz1[i] = bih1[i * 128 + j] + bhh1[i * 128 + j];
      }
#pragma unroll 2
      for (int mt = 0; mt < TC * 4 / 16; ++mt) {
        f32x4 acc[4];
#pragma unroll
        for (int i = 0; i < 4; ++i) acc[i] = (f32x4){0.f, 0.f, 0.f, 0.f};
#pragma unroll
        for (int kt = 0; kt < 4; ++kt) {
          const f16x8 a =
              *(const f16x8*)&hb[(size_t)(mt * 16 + row) * HDIM + kt * 32 + kq * 8];
#pragma unroll
          for (int i = 0; i < 4; ++i) acc[i] = MFMA16(a, Gh[i][kt], acc[i]);
#pragma unroll
          for (int i = 0; i < 4; ++i) acc[i] = MFMA16(a, Gl[i][kt], acc[i]);
        }
#pragma unroll
        for (int r = 0; r < 4; ++r) {
          const int m = mt * 16 + kq * 4 + r;
          float4 o;
          o.x = acc[0][r] + bz1[0];
          o.y = acc[1][r] + bz1[1];
          o.z = acc[2][r] + bz1[2];
          o.w = acc[3][r] + bz1[3];
          *(float4*)&gx[((size_t)m * HDIM + j) * 4] = o;
        }
      }
    }

    float hc[4] = {0, 0, 0, 0}, cc[4] = {0, 0, 0, 0}, wfc = 0.0f;
    const float bfcv = bfc[0];
    if (upd) {
      wfc = Wfc[j];
#pragma unroll
      for (int b = 0; b < 4; ++b) {
        hc[b] = h2s[(size_t)(b0 + b) * HDIM + j];
        cc[b] = c2s[(size_t)(b0 + b) * HDIM + j];
        hfrag1[0][b][j] = f16_bits(hc[b]);
      }
    }
    __syncthreads();  // drains gemm stores (vmcnt) + hfrag1 staging

    f16x8 Rh[4][4], Rl[4][4];
#pragma unroll
    for (int i = 0; i < 4; ++i) {
      const int g = i * 128 + j;
#pragma unroll
      for (int kt = 0; kt < 4; ++kt) {
        const int off = g * HDIM + kt * 32 + kq * 8;
        Rh[i][kt] = *(const f16x8*)&w1h[off];
        Rl[i][kt] = *(const f16x8*)&w1l[off];
      }
    }

    const int t0g = (ch - 1) * TC;
    int cur = 0;
    for (int tt = 0; tt < TC; ++tt) {
      float4 zc[4];
      if (upd) {
#pragma unroll
        for (int b = 0; b < 4; ++b)
          zc[b] = *(const float4*)&gx[((size_t)(tt * 4 + b) * HDIM + j) * 4];
      }
      f32x4 acc[4];
#pragma unroll
      for (int i = 0; i < 4; ++i) acc[i] = (f32x4){0.f, 0.f, 0.f, 0.f};
#pragma unroll
      for (int kt = 0; kt < 4; ++kt) {
        const f16x8 ah = *(const f16x8*)&hfrag1[cur][lane & 3][kt * 32 + kq * 8];
#pragma unroll
        for (int i = 0; i < 4; ++i) acc[i] = MFMA16(ah, Rh[i][kt], acc[i]);
#pragma unroll
        for (int i = 0; i < 4; ++i) acc[i] = MFMA16(ah, Rl[i][kt], acc[i]);
      }
      if (upd) {
        float p[4];
#pragma unroll
        for (int b = 0; b < 4; ++b) {
          const float ig = sigf(acc[0][b] + zc[b].x);
          const float fg = sigf(acc[1][b] + zc[b].y);
          const float gg = tanhf_fast(acc[2][b] + zc[b].z);
          const float og = sigf(acc[3][b] + zc[b].w);
          cc[b] = fg * cc[b] + ig * gg;
          hc[b] = og * tanhf_fast(cc[b]);
          hfrag1[cur ^ 1][b][j] = f16_bits(hc[b]);
          p[b] = fmaxf(hc[b], 0.0f) * wfc;
        }
#pragma unroll
        for (int m = 1; m < 16; m <<= 1) {
#pragma unroll
          for (int b = 0; b < 4; ++b) p[b] += __shfl_xor(p[b], m, 64);
        }
        if (row == 0) {
#pragma unroll
          for (int b = 0; b < 4; ++b) pl[cur][wv][b] = p[b];
        }
      }
      bar_lds();
      if (tid < 4) {
        float s = bfcv;
#pragma unroll
        for (int w8 = 0; w8 < 8; ++w8) s += pl[cur][w8][tid];
        out[(size_t)(b0 + tid) * T_SEQ + t0g + tt] = fmaxf(s, 0.0f);
      }
      cur ^= 1;
    }
    if (upd) {
#pragma unroll
      for (int b = 0; b < 4; ++b) {
        h2s[(size_t)(b0 + b) * HDIM + j] = hc[b];
        c2s[(size_t)(b0 + b) * HDIM + j] = cc[b];
      }
    }
  }
}

extern "C" void kernel_launch(void* const* d_in, const int* in_sizes, int n_in,
                              void* d_out, int out_size, void* d_ws, size_t ws_size,
                              hipStream_t stream)
{
  const float* x    = (const float*)d_in[0];
  const float* Wih0 = (const float*)d_in[1];
  const float* Whh0 = (const float*)d_in[2];
  const float* bih0 = (const float*)d_in[3];
  const float* bhh0 = (const float*)d_in[4];
  const float* Wih1 = (const float*)d_in[5];
  const float* Whh1 = (const float*)d_in[6];
  const float* bih1 = (const float*)d_in[7];
  const float* bhh1 = (const float*)d_in[8];
  const float* Wfc  = (const float*)d_in[9];
  const float* bfc  = (const float*)d_in[10];
  float* out = (float*)d_out;

  const size_t stateN = (size_t)NBATCH * HDIM;  // 65536
  float* h1s = (float*)d_ws;
  float* c1s = h1s + stateN;
  float* h2s = c1s + stateN;
  float* c2s = h2s + stateN;
  ushort_t* w0h  = (ushort_t*)(c2s + stateN);
  ushort_t* w0l  = w0h  + stateN;
  ushort_t* w1h  = w0l  + stateN;
  ushort_t* w1l  = w1h  + stateN;
  ushort_t* wi1h = w1l  + stateN;
  ushort_t* wi1l = wi1h + stateN;
  ushort_t* wxh  = wi1l + stateN;
  ushort_t* wxl  = wxh  + 512 * 32;
  ushort_t* h1buf = wxl + 512 * 32;                       // 2*NWGH*TC*4*HDIM fp16
  float* gx1buf = (float*)(h1buf + (size_t)2 * NWGH * TC * 4 * HDIM);

  // zero-init recurrent states (h0 = c0 = 0)
  (void)hipMemsetAsync(d_ws, 0, 4 * stateN * sizeof(float), stream);
  hipLaunchKernelGGL(prep_weights, dim3(256), dim3(256), 0, stream,
                     Whh0, Whh1, Wih0, Wih1,
                     w0h, w0l, w1h, w1l, wxh, wxl, wi1h, wi1l);

  for (int ch = 0; ch <= NCHUNK; ++ch) {
    hipLaunchKernelGGL(lstm_pipe, dim3(2 * NWGH), dim3(512), 0, stream,
                       x, w0h, w0l, wxh, wxl, bih0, bhh0,
                       wi1h, wi1l, w1h, w1l, bih1, bhh1, Wfc, bfc,
                       out, h1s, c1s, h2s, c2s, h1buf, gx1buf, ch);
  }
}

// Round 11
// 1515.847 us; speedup vs baseline: 7.6892x; 1.3700x over previous
//
#include <hip/hip_runtime.h>

#define T_SEQ  1024
#define NBATCH 512
#define IN_DIM 16
#define HDIM   128
#define G4     (4 * HDIM)
#define TC     64
#define NCHUNK (T_SEQ / TC)
#define NWGH   128   // WGs per role; 4 batches per WG

typedef unsigned short ushort_t;
typedef __attribute__((ext_vector_type(8))) _Float16 f16x8;
typedef __attribute__((ext_vector_type(4))) float f32x4;

#define MFMA16(a, b, c) __builtin_amdgcn_mfma_f32_16x16x32_f16((a), (b), (c), 0, 0, 0)

__device__ __forceinline__ float sigf(float x) {
  return __builtin_amdgcn_rcpf(1.0f + __expf(-x));
}
__device__ __forceinline__ float tanhf_fast(float x) {
  return 1.0f - 2.0f * __builtin_amdgcn_rcpf(1.0f + __expf(2.0f * x));
}
__device__ __forceinline__ ushort_t f16_bits(float f) {
  const _Float16 h = (_Float16)f;
  return __builtin_bit_cast(unsigned short, h);
}
__device__ __forceinline__ void split_f16(float f, ushort_t* hi, ushort_t* lo) {
  const _Float16 h = (_Float16)f;
  *hi = __builtin_bit_cast(unsigned short, h);
  const _Float16 l = (_Float16)(f - (float)h);
  *lo = __builtin_bit_cast(unsigned short, l);
}
// barrier that waits only on LDS ops (global stores stay in flight)
__device__ __forceinline__ void bar_lds() {
  asm volatile("s_waitcnt lgkmcnt(0)\n\ts_barrier" ::: "memory");
}

// ---------------- prep: split weights into fp16 hi/lo ----------------
__global__ __launch_bounds__(256) void prep_weights(
    const float* __restrict__ Whh0, const float* __restrict__ Whh1,
    const float* __restrict__ Wih0, const float* __restrict__ Wih1,
    ushort_t* __restrict__ w0h, ushort_t* __restrict__ w0l,
    ushort_t* __restrict__ w1h, ushort_t* __restrict__ w1l,
    ushort_t* __restrict__ wxh, ushort_t* __restrict__ wxl,
    ushort_t* __restrict__ wi1h, ushort_t* __restrict__ wi1l)
{
  const int idx = blockIdx.x * 256 + threadIdx.x;
  if (idx < 512 * HDIM) {
    split_f16(Whh0[idx], &w0h[idx], &w0l[idx]);
    split_f16(Whh1[idx], &w1h[idx], &w1l[idx]);
    split_f16(Wih1[idx], &wi1h[idx], &wi1l[idx]);
  }
  if (idx < 512 * 32) {  // Wih0 zero-padded K=16 -> 32
    const int g = idx >> 5, k = idx & 31;
    const float f = (k < IN_DIM) ? Wih0[g * IN_DIM + k] : 0.0f;
    split_f16(f, &wxh[idx], &wxl[idx]);
  }
}

// ---------------- pipelined launch: l0(ch) on WGs [0,128), gemm+l1(ch-1) on
// WGs [128,256). Coherence of the h1buf handoff comes from the kernel boundary
// between launches. Gate cols permuted (g = i*128 + wv*16 + row); A rows carry
// batch = row>>2, so C rows kq*4..kq*4+3 all hold batch kq -> EVERY lane
// (kq, col j) owns the full (i,f,g,o) for (batch kq, hidden j) in acc[.][0]:
// the LSTM update runs on all 64 lanes, one batch per lane.
__global__ __launch_bounds__(512, 2) void lstm_pipe(
    const float* __restrict__ x,
    const ushort_t* __restrict__ w0h, const ushort_t* __restrict__ w0l,
    const ushort_t* __restrict__ wxh, const ushort_t* __restrict__ wxl,
    const float* __restrict__ bih0, const float* __restrict__ bhh0,
    const ushort_t* __restrict__ wi1h, const ushort_t* __restrict__ wi1l,
    const ushort_t* __restrict__ w1h, const ushort_t* __restrict__ w1l,
    const float* __restrict__ bih1, const float* __restrict__ bhh1,
    const float* __restrict__ Wfc, const float* __restrict__ bfc,
    float* __restrict__ out,
    float* __restrict__ h1s, float* __restrict__ c1s,
    float* __restrict__ h2s, float* __restrict__ c2s,
    ushort_t* __restrict__ h1buf,   // [2][NWGH][TC*4][HDIM] fp16
    float* __restrict__ gx1buf,     // [NWGH][TC*4][HDIM][4]
    int ch)
{
  const int tid  = threadIdx.x;
  const int lane = tid & 63;
  const int wv   = tid >> 6;
  const int row  = lane & 15;
  const int kq   = lane >> 4;    // = this lane's batch in the update phase
  const int bq   = row >> 2;     // A-fragment batch for this lane's A row
  const int j    = wv * 16 + row;

  if (blockIdx.x < NWGH) {
    // ================= L0 ROLE: chunk ch =================
    if (ch >= NCHUNK) return;
    const int w  = blockIdx.x;
    const int b0 = w * 4;

    __shared__ __align__(16) ushort_t hfrag[2][4][144];
    __shared__ __align__(16) ushort_t xlds[4][TC][32];

    f16x8 Bh[4][4], Bl[4][4], Bxh[4], Bxl[4];
#pragma unroll
    for (int i = 0; i < 4; ++i) {
      const int g = i * 128 + j;
#pragma unroll
      for (int kt = 0; kt < 4; ++kt) {
        const int off = g * HDIM + kt * 32 + kq * 8;
        Bh[i][kt] = *(const f16x8*)&w0h[off];
        Bl[i][kt] = *(const f16x8*)&w0l[off];
      }
      Bxh[i] = *(const f16x8*)&wxh[g * 32 + kq * 8];
      Bxl[i] = *(const f16x8*)&wxl[g * 32 + kq * 8];
    }

    // stage this chunk's x as fp16 (2 threads per (b,ts) row)
    {
      const int r = tid >> 1, half = tid & 1;
      const int b = r >> 6, ts = r & (TC - 1);
      const float* src =
          &x[((size_t)(b0 + b) * T_SEQ + ch * TC + ts) * IN_DIM + half * 8];
      const float4 v0 = *(const float4*)&src[0];
      const float4 v1 = *(const float4*)&src[4];
      ushort_t* dst = &xlds[b][ts][half * 8];
      dst[0] = f16_bits(v0.x); dst[1] = f16_bits(v0.y);
      dst[2] = f16_bits(v0.z); dst[3] = f16_bits(v0.w);
      dst[4] = f16_bits(v1.x); dst[5] = f16_bits(v1.y);
      dst[6] = f16_bits(v1.z); dst[7] = f16_bits(v1.w);
      *(float4*)&xlds[b][ts][16 + half * 8] = (float4){0.f, 0.f, 0.f, 0.f};
    }

    float bz[4];
#pragma unroll
    for (int i = 0; i < 4; ++i) bz[i] = bih0[i * 128 + j] + bhh0[i * 128 + j];
    float hc = h1s[(size_t)(b0 + kq) * HDIM + j];
    float cc = c1s[(size_t)(b0 + kq) * HDIM + j];
    hfrag[0][kq][j] = f16_bits(hc);
    __syncthreads();

    ushort_t* hb = h1buf + ((size_t)(ch & 1) * NWGH + w) * (TC * 4 * HDIM);
    int cur = 0;
    for (int tt = 0; tt < TC; ++tt) {
      const f16x8 ax = *(const f16x8*)&xlds[bq][tt][kq * 8];
      f32x4 acc[4];
#pragma unroll
      for (int i = 0; i < 4; ++i) acc[i] = (f32x4){0.f, 0.f, 0.f, 0.f};
#pragma unroll
      for (int kt = 0; kt < 4; ++kt) {
        const f16x8 ah = *(const f16x8*)&hfrag[cur][bq][kt * 32 + kq * 8];
#pragma unroll
        for (int i = 0; i < 4; ++i) acc[i] = MFMA16(ah, Bh[i][kt], acc[i]);
#pragma unroll
        for (int i = 0; i < 4; ++i) acc[i] = MFMA16(ah, Bl[i][kt], acc[i]);
      }
#pragma unroll
      for (int i = 0; i < 4; ++i) acc[i] = MFMA16(ax, Bxh[i], acc[i]);
#pragma unroll
      for (int i = 0; i < 4; ++i) acc[i] = MFMA16(ax, Bxl[i], acc[i]);

      // in-lane update: batch kq, hidden j, gates in acc[0..3][0]
      {
        const float ig = sigf(acc[0][0] + bz[0]);
        const float fg = sigf(acc[1][0] + bz[1]);
        const float gg = tanhf_fast(acc[2][0] + bz[2]);
        const float og = sigf(acc[3][0] + bz[3]);
        cc = fg * cc + ig * gg;
        hc = og * tanhf_fast(cc);
        const ushort_t hbits = f16_bits(hc);
        hfrag[cur ^ 1][kq][j] = hbits;
        hb[(size_t)(tt * 4 + kq) * HDIM + j] = hbits;
      }
      bar_lds();
      cur ^= 1;
    }
    h1s[(size_t)(b0 + kq) * HDIM + j] = hc;
    c1s[(size_t)(b0 + kq) * HDIM + j] = cc;
  } else {
    // ================= L1 ROLE: gemm + recurrence + FC, chunk ch-1 =========
    if (ch == 0) return;
    const int w  = blockIdx.x - NWGH;
    const int b0 = w * 4;

    __shared__ __align__(16) ushort_t hfrag1[2][4][144];
    __shared__ float pl[2][8][4];

    const ushort_t* hb =
        h1buf + ((size_t)((ch - 1) & 1) * NWGH + w) * (TC * 4 * HDIM);
    float* gx = gx1buf + (size_t)w * (TC * 4 * HDIM * 4);

    // ---- gemm: gx1 = h1 . Wih1^T + biases, own 4 batches only ----
    {
      f16x8 Gh[4][4], Gl[4][4];
      float bz1[4];
#pragma unroll
      for (int i = 0; i < 4; ++i) {
        const int g = i * 128 + j;
#pragma unroll
        for (int kt = 0; kt < 4; ++kt) {
          const int off = g * HDIM + kt * 32 + kq * 8;
          Gh[i][kt] = *(const f16x8*)&wi1h[off];
          Gl[i][kt] = *(const f16x8*)&wi1l[off];
        }
        bz1[i] = bih1[i * 128 + j] + bhh1[i * 128 + j];
      }
#pragma unroll 2
      for (int mt = 0; mt < TC * 4 / 16; ++mt) {
        f32x4 acc[4];
#pragma unroll
        for (int i = 0; i < 4; ++i) acc[i] = (f32x4){0.f, 0.f, 0.f, 0.f};
#pragma unroll
        for (int kt = 0; kt < 4; ++kt) {
          const f16x8 a =
              *(const f16x8*)&hb[(size_t)(mt * 16 + row) * HDIM + kt * 32 + kq * 8];
#pragma unroll
          for (int i = 0; i < 4; ++i) acc[i] = MFMA16(a, Gh[i][kt], acc[i]);
#pragma unroll
          for (int i = 0; i < 4; ++i) acc[i] = MFMA16(a, Gl[i][kt], acc[i]);
        }
#pragma unroll
        for (int r = 0; r < 4; ++r) {
          const int m = mt * 16 + kq * 4 + r;
          float4 o;
          o.x = acc[0][r] + bz1[0];
          o.y = acc[1][r] + bz1[1];
          o.z = acc[2][r] + bz1[2];
          o.w = acc[3][r] + bz1[3];
          *(float4*)&gx[((size_t)m * HDIM + j) * 4] = o;
        }
      }
    }

    const float wfc  = Wfc[j];
    const float bfcv = bfc[0];
    float hc = h2s[(size_t)(b0 + kq) * HDIM + j];
    float cc = c2s[(size_t)(b0 + kq) * HDIM + j];
    hfrag1[0][kq][j] = f16_bits(hc);
    __syncthreads();  // drains gemm stores (vmcnt) + hfrag1 staging

    f16x8 Rh[4][4], Rl[4][4];
#pragma unroll
    for (int i = 0; i < 4; ++i) {
      const int g = i * 128 + j;
#pragma unroll
      for (int kt = 0; kt < 4; ++kt) {
        const int off = g * HDIM + kt * 32 + kq * 8;
        Rh[i][kt] = *(const f16x8*)&w1h[off];
        Rl[i][kt] = *(const f16x8*)&w1l[off];
      }
    }

    const int t0g = (ch - 1) * TC;
    int cur = 0;
    for (int tt = 0; tt < TC; ++tt) {
      const float4 zc = *(const float4*)&gx[((size_t)(tt * 4 + kq) * HDIM + j) * 4];
      f32x4 acc[4];
#pragma unroll
      for (int i = 0; i < 4; ++i) acc[i] = (f32x4){0.f, 0.f, 0.f, 0.f};
#pragma unroll
      for (int kt = 0; kt < 4; ++kt) {
        const f16x8 ah = *(const f16x8*)&hfrag1[cur][bq][kt * 32 + kq * 8];
#pragma unroll
        for (int i = 0; i < 4; ++i) acc[i] = MFMA16(ah, Rh[i][kt], acc[i]);
#pragma unroll
        for (int i = 0; i < 4; ++i) acc[i] = MFMA16(ah, Rl[i][kt], acc[i]);
      }
      // in-lane update + FC partial
      {
        const float ig = sigf(acc[0][0] + zc.x);
        const float fg = sigf(acc[1][0] + zc.y);
        const float gg = tanhf_fast(acc[2][0] + zc.z);
        const float og = sigf(acc[3][0] + zc.w);
        cc = fg * cc + ig * gg;
        hc = og * tanhf_fast(cc);
        hfrag1[cur ^ 1][kq][j] = f16_bits(hc);
        float p = fmaxf(hc, 0.0f) * wfc;
#pragma unroll
        for (int m = 1; m < 16; m <<= 1) p += __shfl_xor(p, m, 64);
        if (row == 0) pl[cur][wv][kq] = p;
      }
      bar_lds();
      if (tid < 4) {
        float s = bfcv;
#pragma unroll
        for (int w8 = 0; w8 < 8; ++w8) s += pl[cur][w8][tid];
        out[(size_t)(b0 + tid) * T_SEQ + t0g + tt] = fmaxf(s, 0.0f);
      }
      cur ^= 1;
    }
    h2s[(size_t)(b0 + kq) * HDIM + j] = hc;
    c2s[(size_t)(b0 + kq) * HDIM + j] = cc;
  }
}

extern "C" void kernel_launch(void* const* d_in, const int* in_sizes, int n_in,
                              void* d_out, int out_size, void* d_ws, size_t ws_size,
                              hipStream_t stream)
{
  const float* x    = (const float*)d_in[0];
  const float* Wih0 = (const float*)d_in[1];
  const float* Whh0 = (const float*)d_in[2];
  const float* bih0 = (const float*)d_in[3];
  const float* bhh0 = (const float*)d_in[4];
  const float* Wih1 = (const float*)d_in[5];
  const float* Whh1 = (const float*)d_in[6];
  const float* bih1 = (const float*)d_in[7];
  const float* bhh1 = (const float*)d_in[8];
  const float* Wfc  = (const float*)d_in[9];
  const float* bfc  = (const float*)d_in[10];
  float* out = (float*)d_out;

  const size_t stateN = (size_t)NBATCH * HDIM;  // 65536
  float* h1s = (float*)d_ws;
  float* c1s = h1s + stateN;
  float* h2s = c1s + stateN;
  float* c2s = h2s + stateN;
  ushort_t* w0h  = (ushort_t*)(c2s + stateN);
  ushort_t* w0l  = w0h  + stateN;
  ushort_t* w1h  = w0l  + stateN;
  ushort_t* w1l  = w1h  + stateN;
  ushort_t* wi1h = w1l  + stateN;
  ushort_t* wi1l = wi1h + stateN;
  ushort_t* wxh  = wi1l + stateN;
  ushort_t* wxl  = wxh  + 512 * 32;
  ushort_t* h1buf = wxl + 512 * 32;                       // 2*NWGH*TC*4*HDIM fp16
  float* gx1buf = (float*)(h1buf + (size_t)2 * NWGH * TC * 4 * HDIM);

  // zero-init recurrent states (h0 = c0 = 0)
  (void)hipMemsetAsync(d_ws, 0, 4 * stateN * sizeof(float), stream);
  hipLaunchKernelGGL(prep_weights, dim3(256), dim3(256), 0, stream,
                     Whh0, Whh1, Wih0, Wih1,
                     w0h, w0l, w1h, w1l, wxh, wxl, wi1h, wi1l);

  for (int ch = 0; ch <= NCHUNK; ++ch) {
    hipLaunchKernelGGL(lstm_pipe, dim3(2 * NWGH), dim3(512), 0, stream,
                       x, w0h, w0l, wxh, wxl, bih0, bhh0,
                       wi1h, wi1l, w1h, w1l, bih1, bhh1, Wfc, bfc,
                       out, h1s, c1s, h2s, c2s, h1buf, gx1buf, ch);
  }
}

// Round 13
// 1298.397 us; speedup vs baseline: 8.9770x; 1.1675x over previous
//
#include <hip/hip_runtime.h>

#define T_SEQ  1024
#define NBATCH 512
#define IN_DIM 16
#define HDIM   128
#define G4     (4 * HDIM)
#define TC     64
#define NCHUNK (T_SEQ / TC)
#define NWGH   128   // WGs per role; 4 batches per WG

typedef unsigned short ushort_t;
typedef __attribute__((ext_vector_type(8))) _Float16 f16x8;
typedef __attribute__((ext_vector_type(4))) float f32x4;

#define MFMA16(a, b, c) __builtin_amdgcn_mfma_f32_16x16x32_f16((a), (b), (c), 0, 0, 0)

__device__ __forceinline__ float sigf(float x) {
  return __builtin_amdgcn_rcpf(1.0f + __expf(-x));
}
__device__ __forceinline__ float tanhf_fast(float x) {
  return 1.0f - 2.0f * __builtin_amdgcn_rcpf(1.0f + __expf(2.0f * x));
}
__device__ __forceinline__ ushort_t f16_bits(float f) {
  const _Float16 h = (_Float16)f;
  return __builtin_bit_cast(unsigned short, h);
}
__device__ __forceinline__ void split_f16(float f, ushort_t* hi, ushort_t* lo) {
  const _Float16 h = (_Float16)f;
  *hi = __builtin_bit_cast(unsigned short, h);
  const _Float16 l = (_Float16)(f - (float)h);
  *lo = __builtin_bit_cast(unsigned short, l);
}
// barrier that waits only on LDS ops (global stores stay in flight)
__device__ __forceinline__ void bar_lds() {
  asm volatile("s_waitcnt lgkmcnt(0)\n\ts_barrier" ::: "memory");
}

// ---------------- prep: split weights into fp16 hi/lo ----------------
__global__ __launch_bounds__(256) void prep_weights(
    const float* __restrict__ Whh0, const float* __restrict__ Whh1,
    const float* __restrict__ Wih0, const float* __restrict__ Wih1,
    ushort_t* __restrict__ w0h, ushort_t* __restrict__ w0l,
    ushort_t* __restrict__ w1h, ushort_t* __restrict__ w1l,
    ushort_t* __restrict__ wxh, ushort_t* __restrict__ wxl,
    ushort_t* __restrict__ wi1h, ushort_t* __restrict__ wi1l)
{
  const int idx = blockIdx.x * 256 + threadIdx.x;
  if (idx < 512 * HDIM) {
    split_f16(Whh0[idx], &w0h[idx], &w0l[idx]);
    split_f16(Whh1[idx], &w1h[idx], &w1l[idx]);
    split_f16(Wih1[idx], &wi1h[idx], &wi1l[idx]);
  }
  if (idx < 512 * 32) {  // Wih0 zero-padded K=16 -> 32
    const int g = idx >> 5, k = idx & 31;
    const float f = (k < IN_DIM) ? Wih0[g * IN_DIM + k] : 0.0f;
    split_f16(f, &wxh[idx], &wxl[idx]);
  }
}

// ---------------- pipelined launch: l0(ch) on WGs [0,128), gemm+l1(ch-1) on
// WGs [128,256). Coherence of the h1buf handoff comes from the kernel boundary
// between launches. Gate cols permuted (g = i*128 + wv*16 + row); A rows carry
// batch = row>>2, so every lane (kq, col j) owns (i,f,g,o) for (batch kq,
// hidden j) -> in-lane update on all 64 lanes. Hi/lo MFMA chains split
// (dep depth 10->5), FC hoisted out of the step loop, zc register prefetch
// (stride: 4 rows x HDIM x 4 floats = 512 float4 PER STEP), pointer-increment
// addressing, 2x-unrolled step loop.
__global__ __launch_bounds__(512, 2) void lstm_pipe(
    const float* __restrict__ x,
    const ushort_t* __restrict__ w0h, const ushort_t* __restrict__ w0l,
    const ushort_t* __restrict__ wxh, const ushort_t* __restrict__ wxl,
    const float* __restrict__ bih0, const float* __restrict__ bhh0,
    const ushort_t* __restrict__ wi1h, const ushort_t* __restrict__ wi1l,
    const ushort_t* __restrict__ w1h, const ushort_t* __restrict__ w1l,
    const float* __restrict__ bih1, const float* __restrict__ bhh1,
    const float* __restrict__ Wfc, const float* __restrict__ bfc,
    float* __restrict__ out,
    float* __restrict__ h1s, float* __restrict__ c1s,
    float* __restrict__ h2s, float* __restrict__ c2s,
    ushort_t* __restrict__ h1buf,   // [2][NWGH][TC*4][HDIM] fp16
    float* __restrict__ gx1buf,     // [NWGH][TC*4][HDIM][4]
    int ch)
{
  const int tid  = threadIdx.x;
  const int lane = tid & 63;
  const int wv   = tid >> 6;
  const int row  = lane & 15;
  const int kq   = lane >> 4;    // = this lane's batch in the update phase
  const int bq   = row >> 2;     // A-fragment batch for this lane's A row
  const int j    = wv * 16 + row;

  if (blockIdx.x < NWGH) {
    // ================= L0 ROLE: chunk ch =================
    if (ch >= NCHUNK) return;
    const int w  = blockIdx.x;
    const int b0 = w * 4;

    __shared__ __align__(16) ushort_t hfA[4][144], hfB[4][144];
    __shared__ __align__(16) ushort_t xlds[4][TC][32];

    f16x8 Bh[4][4], Bl[4][4], Bxh[4], Bxl[4];
#pragma unroll
    for (int i = 0; i < 4; ++i) {
      const int g = i * 128 + j;
#pragma unroll
      for (int kt = 0; kt < 4; ++kt) {
        const int off = g * HDIM + kt * 32 + kq * 8;
        Bh[i][kt] = *(const f16x8*)&w0h[off];
        Bl[i][kt] = *(const f16x8*)&w0l[off];
      }
      Bxh[i] = *(const f16x8*)&wxh[g * 32 + kq * 8];
      Bxl[i] = *(const f16x8*)&wxl[g * 32 + kq * 8];
    }

    // stage this chunk's x as fp16 (2 threads per (b,ts) row)
    {
      const int r = tid >> 1, half = tid & 1;
      const int b = r >> 6, ts = r & (TC - 1);
      const float* src =
          &x[((size_t)(b0 + b) * T_SEQ + ch * TC + ts) * IN_DIM + half * 8];
      const float4 v0 = *(const float4*)&src[0];
      const float4 v1 = *(const float4*)&src[4];
      ushort_t* dst = &xlds[b][ts][half * 8];
      dst[0] = f16_bits(v0.x); dst[1] = f16_bits(v0.y);
      dst[2] = f16_bits(v0.z); dst[3] = f16_bits(v0.w);
      dst[4] = f16_bits(v1.x); dst[5] = f16_bits(v1.y);
      dst[6] = f16_bits(v1.z); dst[7] = f16_bits(v1.w);
      *(float4*)&xlds[b][ts][16 + half * 8] = (float4){0.f, 0.f, 0.f, 0.f};
    }

    float bz[4];
#pragma unroll
    for (int i = 0; i < 4; ++i) bz[i] = bih0[i * 128 + j] + bhh0[i * 128 + j];
    float hc = h1s[(size_t)(b0 + kq) * HDIM + j];
    float cc = c1s[(size_t)(b0 + kq) * HDIM + j];
    hfA[kq][j] = f16_bits(hc);
    __syncthreads();

    ushort_t* hbp = h1buf + ((size_t)(ch & 1) * NWGH + w) * (TC * 4 * HDIM) +
                    (size_t)kq * HDIM + j;

#define L0_STEP(HIN, HOUT, TT)                                              \
  {                                                                         \
    const f16x8 ax = *(const f16x8*)&xlds[bq][TT][kq * 8];                  \
    f32x4 aH[4], aL[4];                                                     \
    _Pragma("unroll") for (int i = 0; i < 4; ++i) {                         \
      aH[i] = (f32x4){0.f, 0.f, 0.f, 0.f};                                  \
      aL[i] = (f32x4){0.f, 0.f, 0.f, 0.f};                                  \
    }                                                                       \
    _Pragma("unroll") for (int kt = 0; kt < 4; ++kt) {                      \
      const f16x8 ah = *(const f16x8*)&HIN[bq][kt * 32 + kq * 8];           \
      _Pragma("unroll") for (int i = 0; i < 4; ++i)                         \
          aH[i] = MFMA16(ah, Bh[i][kt], aH[i]);                             \
      _Pragma("unroll") for (int i = 0; i < 4; ++i)                         \
          aL[i] = MFMA16(ah, Bl[i][kt], aL[i]);                             \
    }                                                                       \
    _Pragma("unroll") for (int i = 0; i < 4; ++i)                           \
        aH[i] = MFMA16(ax, Bxh[i], aH[i]);                                  \
    _Pragma("unroll") for (int i = 0; i < 4; ++i)                           \
        aL[i] = MFMA16(ax, Bxl[i], aL[i]);                                  \
    const float ig = sigf(aH[0][0] + aL[0][0] + bz[0]);                     \
    const float fg = sigf(aH[1][0] + aL[1][0] + bz[1]);                     \
    const float gg = tanhf_fast(aH[2][0] + aL[2][0] + bz[2]);               \
    const float og = sigf(aH[3][0] + aL[3][0] + bz[3]);                     \
    cc = fg * cc + ig * gg;                                                 \
    hc = og * tanhf_fast(cc);                                               \
    const ushort_t hbits = f16_bits(hc);                                    \
    HOUT[kq][j] = hbits;                                                    \
    *hbp = hbits;                                                           \
    hbp += 4 * HDIM;                                                        \
    bar_lds();                                                              \
  }

    for (int tt = 0; tt < TC; tt += 2) {
      L0_STEP(hfA, hfB, tt);
      L0_STEP(hfB, hfA, tt + 1);
    }
#undef L0_STEP

    h1s[(size_t)(b0 + kq) * HDIM + j] = hc;
    c1s[(size_t)(b0 + kq) * HDIM + j] = cc;
  } else {
    // ================= L1 ROLE: gemm + recurrence, FC at chunk end =========
    if (ch == 0) return;
    const int w  = blockIdx.x - NWGH;
    const int b0 = w * 4;

    __shared__ __align__(16) ushort_t hf1A[4][144], hf1B[4][144];
    __shared__ __align__(16) ushort_t h2l[TC][4][136];  // fp16 h2 for FC pass
    __shared__ float wfl[HDIM];

    const ushort_t* hb =
        h1buf + ((size_t)((ch - 1) & 1) * NWGH + w) * (TC * 4 * HDIM);
    float* gx = gx1buf + (size_t)w * (TC * 4 * HDIM * 4);

    if (tid < HDIM) wfl[tid] = Wfc[tid];

    // ---- gemm: gx1 = h1 . Wih1^T + biases, own 4 batches only ----
    {
      f16x8 Gh[4][4], Gl[4][4];
      float bz1[4];
#pragma unroll
      for (int i = 0; i < 4; ++i) {
        const int g = i * 128 + j;
#pragma unroll
        for (int kt = 0; kt < 4; ++kt) {
          const int off = g * HDIM + kt * 32 + kq * 8;
          Gh[i][kt] = *(const f16x8*)&wi1h[off];
          Gl[i][kt] = *(const f16x8*)&wi1l[off];
        }
        bz1[i] = bih1[i * 128 + j] + bhh1[i * 128 + j];
      }
#pragma unroll 2
      for (int mt = 0; mt < TC * 4 / 16; ++mt) {
        f32x4 acc[4];
#pragma unroll
        for (int i = 0; i < 4; ++i) acc[i] = (f32x4){0.f, 0.f, 0.f, 0.f};
#pragma unroll
        for (int kt = 0; kt < 4; ++kt) {
          const f16x8 a =
              *(const f16x8*)&hb[(size_t)(mt * 16 + row) * HDIM + kt * 32 + kq * 8];
#pragma unroll
          for (int i = 0; i < 4; ++i) acc[i] = MFMA16(a, Gh[i][kt], acc[i]);
#pragma unroll
          for (int i = 0; i < 4; ++i) acc[i] = MFMA16(a, Gl[i][kt], acc[i]);
        }
#pragma unroll
        for (int r = 0; r < 4; ++r) {
          const int m = mt * 16 + kq * 4 + r;
          float4 o;
          o.x = acc[0][r] + bz1[0];
          o.y = acc[1][r] + bz1[1];
          o.z = acc[2][r] + bz1[2];
          o.w = acc[3][r] + bz1[3];
          *(float4*)&gx[((size_t)m * HDIM + j) * 4] = o;
        }
      }
    }

    float hc = h2s[(size_t)(b0 + kq) * HDIM + j];
    float cc = c2s[(size_t)(b0 + kq) * HDIM + j];
    hf1A[kq][j] = f16_bits(hc);
    __syncthreads();  // drains gemm stores (vmcnt) + hf1A/wfl staging

    f16x8 Rh[4][4], Rl[4][4];
#pragma unroll
    for (int i = 0; i < 4; ++i) {
      const int g = i * 128 + j;
#pragma unroll
      for (int kt = 0; kt < 4; ++kt) {
        const int off = g * HDIM + kt * 32 + kq * 8;
        Rh[i][kt] = *(const f16x8*)&w1h[off];
        Rl[i][kt] = *(const f16x8*)&w1l[off];
      }
    }

    // per-step stride: 4 rows x HDIM x 4 floats = 2048 floats = 512 float4
    const float4* gxp = (const float4*)&gx[((size_t)kq * HDIM + j) * 4];
    float4 zcc = *gxp;
    gxp += 512;

#define L1_STEP(HIN, HOUT, TT)                                              \
  {                                                                         \
    const float4 zcu = zcc;                                                 \
    if ((TT) + 1 < TC) { zcc = *gxp; gxp += 512; }                          \
    f32x4 aH[4], aL[4];                                                     \
    _Pragma("unroll") for (int i = 0; i < 4; ++i) {                         \
      aH[i] = (f32x4){0.f, 0.f, 0.f, 0.f};                                  \
      aL[i] = (f32x4){0.f, 0.f, 0.f, 0.f};                                  \
    }                                                                       \
    _Pragma("unroll") for (int kt = 0; kt < 4; ++kt) {                      \
      const f16x8 ah = *(const f16x8*)&HIN[bq][kt * 32 + kq * 8];           \
      _Pragma("unroll") for (int i = 0; i < 4; ++i)                         \
          aH[i] = MFMA16(ah, Rh[i][kt], aH[i]);                             \
      _Pragma("unroll") for (int i = 0; i < 4; ++i)                         \
          aL[i] = MFMA16(ah, Rl[i][kt], aL[i]);                             \
    }                                                                       \
    const float ig = sigf(aH[0][0] + aL[0][0] + zcu.x);                     \
    const float fg = sigf(aH[1][0] + aL[1][0] + zcu.y);                     \
    const float gg = tanhf_fast(aH[2][0] + aL[2][0] + zcu.z);               \
    const float og = sigf(aH[3][0] + aL[3][0] + zcu.w);                     \
    cc = fg * cc + ig * gg;                                                 \
    hc = og * tanhf_fast(cc);                                               \
    const ushort_t hbits = f16_bits(hc);                                    \
    HOUT[kq][j] = hbits;                                                    \
    h2l[TT][kq][j] = hbits;                                                 \
    bar_lds();                                                              \
  }

    for (int tt = 0; tt < TC; tt += 2) {
      L1_STEP(hf1A, hf1B, tt);
      L1_STEP(hf1B, hf1A, tt + 1);
    }
#undef L1_STEP

    h2s[(size_t)(b0 + kq) * HDIM + j] = hc;
    c2s[(size_t)(b0 + kq) * HDIM + j] = cc;

    // ---- FC pass over the chunk (latency-tolerant, once per chunk) ----
    // last bar_lds already made all h2l writes visible
    if (tid < TC * 4) {
      const int tt = tid >> 2, b = tid & 3;
      const float bfcv = bfc[0];
      float s0 = 0.f, s1 = 0.f, s2 = 0.f, s3 = 0.f;
#pragma unroll
      for (int q = 0; q < HDIM / 8; ++q) {
        const f16x8 hv = *(const f16x8*)&h2l[tt][b][q * 8];
        const float* wq = &wfl[q * 8];
        s0 += fmaxf((float)hv[0], 0.f) * wq[0];
        s1 += fmaxf((float)hv[1], 0.f) * wq[1];
        s2 += fmaxf((float)hv[2], 0.f) * wq[2];
        s3 += fmaxf((float)hv[3], 0.f) * wq[3];
        s0 += fmaxf((float)hv[4], 0.f) * wq[4];
        s1 += fmaxf((float)hv[5], 0.f) * wq[5];
        s2 += fmaxf((float)hv[6], 0.f) * wq[6];
        s3 += fmaxf((float)hv[7], 0.f) * wq[7];
      }
      const float s = s0 + s1 + s2 + s3 + bfcv;
      out[(size_t)(b0 + b) * T_SEQ + (ch - 1) * TC + tt] = fmaxf(s, 0.0f);
    }
  }
}

extern "C" void kernel_launch(void* const* d_in, const int* in_sizes, int n_in,
                              void* d_out, int out_size, void* d_ws, size_t ws_size,
                              hipStream_t stream)
{
  const float* x    = (const float*)d_in[0];
  const float* Wih0 = (const float*)d_in[1];
  const float* Whh0 = (const float*)d_in[2];
  const float* bih0 = (const float*)d_in[3];
  const float* bhh0 = (const float*)d_in[4];
  const float* Wih1 = (const float*)d_in[5];
  const float* Whh1 = (const float*)d_in[6];
  const float* bih1 = (const float*)d_in[7];
  const float* bhh1 = (const float*)d_in[8];
  const float* Wfc  = (const float*)d_in[9];
  const float* bfc  = (const float*)d_in[10];
  float* out = (float*)d_out;

  const size_t stateN = (size_t)NBATCH * HDIM;  // 65536
  float* h1s = (float*)d_ws;
  float* c1s = h1s + stateN;
  float* h2s = c1s + stateN;
  float* c2s = h2s + stateN;
  ushort_t* w0h  = (ushort_t*)(c2s + stateN);
  ushort_t* w0l  = w0h  + stateN;
  ushort_t* w1h  = w0l  + stateN;
  ushort_t* w1l  = w1h  + stateN;
  ushort_t* wi1h = w1l  + stateN;
  ushort_t* wi1l = wi1h + stateN;
  ushort_t* wxh  = wi1l + stateN;
  ushort_t* wxl  = wxh  + 512 * 32;
  ushort_t* h1buf = wxl + 512 * 32;                       // 2*NWGH*TC*4*HDIM fp16
  float* gx1buf = (float*)(h1buf + (size_t)2 * NWGH * TC * 4 * HDIM);

  // zero-init recurrent states (h0 = c0 = 0)
  (void)hipMemsetAsync(d_ws, 0, 4 * stateN * sizeof(float), stream);
  hipLaunchKernelGGL(prep_weights, dim3(256), dim3(256), 0, stream,
                     Whh0, Whh1, Wih0, Wih1,
                     w0h, w0l, w1h, w1l, wxh, wxl, wi1h, wi1l);

  for (int ch = 0; ch <= NCHUNK; ++ch) {
    hipLaunchKernelGGL(lstm_pipe, dim3(2 * NWGH), dim3(512), 0, stream,
                       x, w0h, w0l, wxh, wxl, bih0, bhh0,
                       wi1h, wi1l, w1h, w1l, bih1, bhh1, Wfc, bfc,
                       out, h1s, c1s, h2s, c2s, h1buf, gx1buf, ch);
  }
}